// Round 13
// baseline (438.875 us; speedup 1.0000x reference)
//
#include <hip/hip_runtime.h>

#define S_LEN 512
#define BSZ 8
#define NH 8
#define HD 64
#define IN_DIM 512
#define PROJ 2576   // NH*(5*HD+2)
#define SEG 322     // per-head: 5*64+2
#define AST 352     // act row stride f32: q64,k64,rk64,v64,rv64,beta,rbeta,pad -> 8 rows = 11*1024B
#define CHUNK 8
#define NCH 64      // 512/CHUNK
#define CB (CHUNK * AST * 4)  // 11264 bytes per chunk

typedef __attribute__((ext_vector_type(8))) __bf16 bf16x8;
typedef __attribute__((ext_vector_type(4))) float f32x4;
typedef __attribute__((ext_vector_type(2))) float f32x2;

typedef union { f32x4 v4; f32x2 v2[2]; float f[4]; } u4;

static __device__ __forceinline__ unsigned short f2bf(float f) {
  unsigned u = __float_as_uint(f);
  unsigned r = (u + 0x7fffu + ((u >> 16) & 1u)) >> 16;
  return (unsigned short)r;
}
static __device__ __forceinline__ float bf2f(unsigned short s) {
  return __uint_as_float(((unsigned)s) << 16);
}

// packed 2-wide FMA / ADD (compiler does not auto-form VOP3P f32 ops).
// Pure (non-volatile, register-only) asm: scheduler may reorder freely.
static __device__ __forceinline__ f32x2 pk_fma(f32x2 a, f32x2 b, f32x2 c) {
  f32x2 d;
  asm("v_pk_fma_f32 %0, %1, %2, %3" : "=v"(d) : "v"(a), "v"(b), "v"(c));
  return d;
}
static __device__ __forceinline__ f32x2 pk_add(f32x2 a, f32x2 b) {
  f32x2 d;
  asm("v_pk_add_f32 %0, %1, %2" : "=v"(d) : "v"(a), "v"(b));
  return d;
}

static __device__ __forceinline__ void gl_lds16(const void* g, void* l) {
  __builtin_amdgcn_global_load_lds(
      (const __attribute__((address_space(1))) unsigned int*)g,
      (__attribute__((address_space(3))) unsigned int*)l, 16, 0, 0);
}

// ---------------- LayerNorm: x (4096x512 f32) -> normed bf16 ----------------
__global__ __launch_bounds__(256) void ln_kernel(const float* __restrict__ x,
                                                 const float* __restrict__ gamma,
                                                 const float* __restrict__ beta,
                                                 unsigned short* __restrict__ out) {
  int wave = threadIdx.x >> 6, lane = threadIdx.x & 63;
  int row = blockIdx.x * 4 + wave;
  const float* xr = x + (size_t)row * IN_DIM + lane * 8;
  float4 a = *(const float4*)xr;
  float4 b = *(const float4*)(xr + 4);
  float vals[8] = {a.x, a.y, a.z, a.w, b.x, b.y, b.z, b.w};
  float s = 0.f, ss = 0.f;
#pragma unroll
  for (int i = 0; i < 8; i++) { s += vals[i]; ss += vals[i] * vals[i]; }
#pragma unroll
  for (int o = 32; o; o >>= 1) { s += __shfl_xor(s, o); ss += __shfl_xor(ss, o); }
  float mu = s * (1.f / 512.f);
  float var = ss * (1.f / 512.f) - mu * mu;
  float rstd = rsqrtf(var + 1e-5f);
  const float* g = gamma + lane * 8;
  const float* be = beta + lane * 8;
  float4 g1 = *(const float4*)g, g2 = *(const float4*)(g + 4);
  float4 b1 = *(const float4*)be, b2 = *(const float4*)(be + 4);
  float gs[8] = {g1.x, g1.y, g1.z, g1.w, g2.x, g2.y, g2.z, g2.w};
  float bs[8] = {b1.x, b1.y, b1.z, b1.w, b2.x, b2.y, b2.z, b2.w};
  union { unsigned short u[8]; uint4 v; } pk;
#pragma unroll
  for (int i = 0; i < 8; i++) pk.u[i] = f2bf((vals[i] - mu) * rstd * gs[i] + bs[i]);
  *(uint4*)(out + (size_t)row * IN_DIM + lane * 8) = pk.v;
}

// ---------------- generic f32 -> bf16 cast ----------------
__global__ void cast_kernel(const float* __restrict__ in, unsigned short* __restrict__ out, int n) {
  int i = blockIdx.x * blockDim.x + threadIdx.x;
  int st = gridDim.x * blockDim.x;
  for (; i < n; i += st) out[i] = f2bf(in[i]);
}

// ---------------- GEMM 128x128 tile: C[m][n] = sum_k A[m][k]*B[n][k] ----------------
template <int BF16_OUT, int RESID>
__global__ __launch_bounds__(256) void gemm128(const unsigned short* __restrict__ A,
                                               const unsigned short* __restrict__ B,
                                               void* __restrict__ Cout,
                                               const float* __restrict__ resid,
                                               int M, int N, int K) {
  __shared__ __align__(16) unsigned short As[128 * 32];
  __shared__ __align__(16) unsigned short Bs[128 * 32];
  int tid = threadIdx.x;
  int lane = tid & 63, w = tid >> 6;
  int wr = w >> 1, wc = w & 1;
  int m0 = blockIdx.y * 128, n0 = blockIdx.x * 128;

  int r0 = (w * 2) * 16 + (lane >> 2);
  int r1 = (w * 2 + 1) * 16 + (lane >> 2);
  int kq = (lane & 3) * 8;
  const unsigned short* A0 = A + (size_t)(m0 + r0) * K + kq;
  const unsigned short* A1 = A + (size_t)(m0 + r1) * K + kq;
  int bn0 = n0 + r0; if (bn0 > N - 1) bn0 = N - 1;
  int bn1 = n0 + r1; if (bn1 > N - 1) bn1 = N - 1;
  const unsigned short* B0 = B + (size_t)bn0 * K + kq;
  const unsigned short* B1 = B + (size_t)bn1 * K + kq;
  char* asb0 = (char*)As + (w * 2) * 1024;
  char* asb1 = (char*)As + (w * 2 + 1) * 1024;
  char* bsb0 = (char*)Bs + (w * 2) * 1024;
  char* bsb1 = (char*)Bs + (w * 2 + 1) * 1024;

  f32x4 acc[4][4];
#pragma unroll
  for (int i = 0; i < 4; i++)
#pragma unroll
    for (int j = 0; j < 4; j++) acc[i][j] = (f32x4){0.f, 0.f, 0.f, 0.f};

  int q = lane >> 4, m16 = lane & 15;
  for (int k0 = 0; k0 < K; k0 += 32) {
    gl_lds16(A0 + k0, asb0);
    gl_lds16(A1 + k0, asb1);
    gl_lds16(B0 + k0, bsb0);
    gl_lds16(B1 + k0, bsb1);
    asm volatile("s_waitcnt vmcnt(0)" ::: "memory");
    __syncthreads();
    bf16x8 af[4], bfv[4];
#pragma unroll
    for (int f = 0; f < 4; f++)
      af[f] = *(const bf16x8*)&As[(wr * 64 + f * 16 + m16) * 32 + q * 8];
#pragma unroll
    for (int f = 0; f < 4; f++)
      bfv[f] = *(const bf16x8*)&Bs[(wc * 64 + f * 16 + m16) * 32 + q * 8];
#pragma unroll
    for (int fa = 0; fa < 4; fa++)
#pragma unroll
      for (int fb = 0; fb < 4; fb++)
        acc[fa][fb] = __builtin_amdgcn_mfma_f32_16x16x32_bf16(af[fa], bfv[fb], acc[fa][fb], 0, 0, 0);
    __syncthreads();
  }

#pragma unroll
  for (int fa = 0; fa < 4; fa++) {
#pragma unroll
    for (int fb = 0; fb < 4; fb++) {
#pragma unroll
      for (int rr = 0; rr < 4; rr++) {
        int gm = m0 + wr * 64 + fa * 16 + q * 4 + rr;
        int gn = n0 + wc * 64 + fb * 16 + m16;
        if (gn < N) {
          float v = acc[fa][fb][rr];
          if (BF16_OUT) {
            ((unsigned short*)Cout)[(size_t)gm * N + gn] = f2bf(v);
          } else {
            float o = v;
            if (RESID) o += resid[(size_t)gm * N + gn];
            ((float*)Cout)[(size_t)gm * N + gn] = o;
          }
        }
      }
    }
  }
}

// ---------------- parallel activations -> act stream (f32) ----------------
__global__ __launch_bounds__(256) void act_kernel(const unsigned short* __restrict__ qkvb,
                                                  float* __restrict__ act) {
  int gw = blockIdx.x * 4 + (threadIdx.x >> 6);
  int l = threadIdx.x & 63;
  int m = gw >> 3, hh = gw & 7;
  int t = m >> 3, b = m & 7;
  const unsigned short* src = qkvb + (size_t)m * PROJ + hh * SEG;
  float fq = bf2f(src[l]);
  float fk = bf2f(src[64 + l]);
  float fv = bf2f(src[128 + l]);
  float fr = bf2f(src[192 + l]);
  float frv = bf2f(src[256 + l]);
  float mq = fq, mk = fk, mr = fr;
#pragma unroll
  for (int o = 32; o; o >>= 1) {
    mq = fmaxf(mq, __shfl_xor(mq, o));
    mk = fmaxf(mk, __shfl_xor(mk, o));
    mr = fmaxf(mr, __shfl_xor(mr, o));
  }
  float eq = __expf(fq - mq), ek = __expf(fk - mk), er = __expf(fr - mr);
  float sq = eq, sk = ek, sr = er;
#pragma unroll
  for (int o = 32; o; o >>= 1) {
    sq += __shfl_xor(sq, o);
    sk += __shfl_xor(sk, o);
    sr += __shfl_xor(sr, o);
  }
  int bh = b * 8 + hh;
  float* dst = act + ((size_t)bh * S_LEN + t) * AST;
  dst[l] = eq * __builtin_amdgcn_rcpf(sq);
  dst[64 + l] = ek * __builtin_amdgcn_rcpf(sk);
  dst[128 + l] = er * __builtin_amdgcn_rcpf(sr);
  dst[192 + l] = fv;
  dst[256 + l] = frv;
  if (l < 2) {
    float xv = bf2f(src[320 + l]);
    dst[320 + l] = __builtin_amdgcn_rcpf(1.f + __expf(-xv));
  }
}

// ---------------- scan: R4 async skeleton + v_pk_fma_f32 bodies (no pins) ----------------
// Block = 128 threads = 2 waves per (b,h). Wave0 (producer): stages act chunks via
// global_load_lds, runs the delta-rule W-scan, deposits z into a 4-chunk LDS ring,
// publishes per-chunk flags. Wave1 (consumer): polls the flag once per chunk,
// runs the recurrent R-scan. Ring/flags/vmcnt protocol byte-identical to the
// verified 276us round-4 kernel. Only change: state f32x2 M2[32] and all FMA
// streams as v_pk_fma_f32 (halves FMA issue, 512->256 cyc/step/wave). LDS reads
// unchanged (16 x ds_read_b128 via u4 unions). R5's regression was the pins
// (16 lgkm waits between loads and pass-1), not the packing - this isolates it.
__global__ __launch_bounds__(128, 1) void scan_kernel(const float* __restrict__ act,
                                                      unsigned short* __restrict__ hs) {
  int bh = blockIdx.x;
  int b = bh >> 3, hh = bh & 7;
  int tid = threadIdx.x, l = tid & 63, w = tid >> 6;

  __shared__ __align__(16) float stage[4][CHUNK * AST];
  __shared__ __align__(16) float zring[4][CHUNK][64];
  __shared__ __align__(16) float ehb[64];
  __shared__ int flags[16];  // [0]=w0done (chunks), [8]=w1done (chunks)

  volatile int* w0done = &flags[0];
  volatile int* w1done = &flags[8];

  const char* abase = (const char*)(act + (size_t)bh * S_LEN * AST);

  if (tid == 0) { flags[0] = 0; flags[8] = 0; }
  if (w) ehb[l] = 1.f;  // softmax(h0=0) numerators -> uniform
  if (w == 0) {
    // stage chunk 0
#pragma unroll
    for (int i = 0; i < 11; i++)
      gl_lds16(abase + (size_t)i * 1024 + l * 16, (char*)&stage[0][0] + i * 1024);
  }
  __syncthreads();  // flags/ehb init visible; drains wave0's chunk-0 staging too

  f32x2 M2[32];
#pragma unroll
  for (int j = 0; j < 32; j++) M2[j] = (f32x2){0.f, 0.f};
  const f32x2 zz = {0.f, 0.f};

  if (w == 0) {
    // ================= producer: W-scan =================
    for (int c = 0; c < NCH; c++) {
      // back-pressure: staging into slot (c+1)&3 overwrites chunk c-3
      if (c >= 3) {
        while (*w1done < c - 2) __builtin_amdgcn_s_sleep(2);
      }
      if (c + 1 < NCH) {
        const char* nb = abase + (size_t)(c + 1) * CB;
        char* sb = (char*)&stage[(c + 1) & 3][0];
#pragma unroll
        for (int i = 0; i < 11; i++)
          gl_lds16(nb + (size_t)i * 1024 + l * 16, sb + i * 1024);
        asm volatile("s_waitcnt vmcnt(11)" ::: "memory");  // chunk c's staging done
      } else {
        asm volatile("s_waitcnt vmcnt(0)" ::: "memory");
      }
      const float* cb = &stage[c & 3][0];
      float* zc = &zring[c & 3][0][0];
#pragma unroll
      for (int s = 0; s < CHUNK; s++) {
        const float* stf = cb + s * AST;
        const f32x4* st4 = (const f32x4*)stf;
        // ---- vold = W.k; fused W += coef*k, z = W.q ----
        float cv = stf[192 + l];
        float bt = stf[320];
        u4 kv[16];
#pragma unroll
        for (int j = 0; j < 16; j++) kv[j].v4 = st4[16 + j];  // k (16x b128)
        f32x2 a0 = zz, a1 = zz, a2 = zz, a3 = zz;
#pragma unroll
        for (int j = 0; j < 16; j += 2) {
          a0 = pk_fma(M2[2 * j],     kv[j].v2[0],     a0);
          a1 = pk_fma(M2[2 * j + 1], kv[j].v2[1],     a1);
          a2 = pk_fma(M2[2 * j + 2], kv[j + 1].v2[0], a2);
          a3 = pk_fma(M2[2 * j + 3], kv[j + 1].v2[1], a3);
        }
        f32x2 vo = pk_add(pk_add(a0, a1), pk_add(a2, a3));
        float vold = vo.x + vo.y;
        float coef = bt * (cv - vold);
        f32x2 c2 = {coef, coef};
        a0 = a1 = a2 = a3 = zz;
#pragma unroll
        for (int j = 0; j < 16; j += 2) {
          u4 qA, qB;
          qA.v4 = st4[j];
          qB.v4 = st4[j + 1];
          M2[2 * j]     = pk_fma(c2, kv[j].v2[0],     M2[2 * j]);
          a0 = pk_fma(M2[2 * j],     qA.v2[0], a0);
          M2[2 * j + 1] = pk_fma(c2, kv[j].v2[1],     M2[2 * j + 1]);
          a1 = pk_fma(M2[2 * j + 1], qA.v2[1], a1);
          M2[2 * j + 2] = pk_fma(c2, kv[j + 1].v2[0], M2[2 * j + 2]);
          a2 = pk_fma(M2[2 * j + 2], qB.v2[0], a2);
          M2[2 * j + 3] = pk_fma(c2, kv[j + 1].v2[1], M2[2 * j + 3]);
          a3 = pk_fma(M2[2 * j + 3], qB.v2[1], a3);
        }
        vo = pk_add(pk_add(a0, a1), pk_add(a2, a3));
        zc[s * 64 + l] = vo.x + vo.y;
      }
      asm volatile("s_waitcnt lgkmcnt(0)" ::: "memory");  // z writes retired
      *w0done = c + 1;
    }
  } else {
    // ================= consumer: R-scan =================
    unsigned short* hdst = hs + (size_t)b * 512 + hh * 64 + l;
    for (int c = 0; c < NCH; c++) {
      while (*w0done < c + 1) __builtin_amdgcn_s_sleep(2);  // chunk c staged + z ready
      const float* cb = &stage[c & 3][0];
      const float* zc = &zring[c & 3][0][0];
#pragma unroll
      for (int s = 0; s < CHUNK; s++) {
        const float* stf = cb + s * AST;
        const f32x4* st4 = (const f32x4*)stf;
        float z = zc[s * 64 + l];  // issue early; latency hides under matvec
        // ---- rvold = R.rk; fused R += rcoef*rk, hp = R.eh, sm = sum(eh) ----
        float cv = stf[256 + l];
        float rb = stf[321];
        u4 kv[16];
#pragma unroll
        for (int j = 0; j < 16; j++) kv[j].v4 = st4[32 + j];  // rk (16x b128)
        f32x2 a0 = zz, a1 = zz, a2 = zz, a3 = zz;
#pragma unroll
        for (int j = 0; j < 16; j += 2) {
          a0 = pk_fma(M2[2 * j],     kv[j].v2[0],     a0);
          a1 = pk_fma(M2[2 * j + 1], kv[j].v2[1],     a1);
          a2 = pk_fma(M2[2 * j + 2], kv[j + 1].v2[0], a2);
          a3 = pk_fma(M2[2 * j + 3], kv[j + 1].v2[1], a3);
        }
        f32x2 vo = pk_add(pk_add(a0, a1), pk_add(a2, a3));
        float rvold = vo.x + vo.y;
        float rcoef = rb * (cv - rvold);
        f32x2 rc2 = {rcoef, rcoef};
        const f32x4* e4 = (const f32x4*)ehb;
        f32x2 s0 = zz, s1 = zz;
        a0 = a1 = a2 = a3 = zz;
#pragma unroll
        for (int j = 0; j < 16; j += 2) {
          u4 eA, eB;
          eA.v4 = e4[j];
          eB.v4 = e4[j + 1];
          M2[2 * j]     = pk_fma(rc2, kv[j].v2[0],     M2[2 * j]);
          a0 = pk_fma(M2[2 * j],     eA.v2[0], a0);
          M2[2 * j + 1] = pk_fma(rc2, kv[j].v2[1],     M2[2 * j + 1]);
          a1 = pk_fma(M2[2 * j + 1], eA.v2[1], a1);
          M2[2 * j + 2] = pk_fma(rc2, kv[j + 1].v2[0], M2[2 * j + 2]);
          a2 = pk_fma(M2[2 * j + 2], eB.v2[0], a2);
          M2[2 * j + 3] = pk_fma(rc2, kv[j + 1].v2[1], M2[2 * j + 3]);
          a3 = pk_fma(M2[2 * j + 3], eB.v2[1], a3);
          s0 = pk_add(s0, pk_add(eA.v2[0], eA.v2[1]));
          s1 = pk_add(s1, pk_add(eB.v2[0], eB.v2[1]));
        }
        f32x2 ho = pk_add(pk_add(a0, a1), pk_add(a2, a3));
        f32x2 sv = pk_add(s0, s1);
        float hp = ho.x + ho.y;
        float sm = sv.x + sv.y;
        float h = z + hp * __builtin_amdgcn_rcpf(sm);
        hdst[(size_t)(c * CHUNK + s) * (BSZ * 512)] = f2bf(h);
        // shift-invariant: exp(h-20) keeps qh = eh/sum exact, guards overflow.
        // same-wave DS ordering makes it visible to next step's e4 reads.
        ehb[l] = __expf(h - 20.f);
      }
      asm volatile("s_waitcnt lgkmcnt(0)" ::: "memory");  // all chunk-c reads retired
      *w1done = c + 1;
    }
  }
}

extern "C" void kernel_launch(void* const* d_in, const int* in_sizes, int n_in,
                              void* d_out, int out_size, void* d_ws, size_t ws_size,
                              hipStream_t stream) {
  const float* x = (const float*)d_in[0];
  const float* W_slow = (const float*)d_in[1];
  const float* W_out = (const float*)d_in[2];
  const float* gamma = (const float*)d_in[3];
  const float* beta = (const float*)d_in[4];

  char* ws = (char*)d_ws;
  size_t off = 0;
  unsigned short* normed = (unsigned short*)(ws + off); off += (size_t)4096 * 512 * 2;
  unsigned short* Wslow_b = (unsigned short*)(ws + off); off += (size_t)PROJ * 512 * 2;
  unsigned short* Wout_b = (unsigned short*)(ws + off); off += (size_t)512 * 512 * 2;
  unsigned short* qkvb = (unsigned short*)(ws + off); off += (size_t)4096 * PROJ * 2;
  float* act = (float*)(ws + off); off += (size_t)64 * S_LEN * AST * 4;
  unsigned short* hsb = normed;  // normed is dead after gemm1; reuse for hs

  hipLaunchKernelGGL(ln_kernel, dim3(1024), dim3(256), 0, stream, x, gamma, beta, normed);
  hipLaunchKernelGGL(cast_kernel, dim3(512), dim3(256), 0, stream, W_slow, Wslow_b, PROJ * 512);
  hipLaunchKernelGGL(cast_kernel, dim3(256), dim3(256), 0, stream, W_out, Wout_b, 512 * 512);
  hipLaunchKernelGGL((gemm128<1, 0>), dim3((PROJ + 127) / 128, 4096 / 128), dim3(256), 0, stream,
                     normed, Wslow_b, (void*)qkvb, (const float*)nullptr, 4096, PROJ, 512);
  hipLaunchKernelGGL(act_kernel, dim3(8192), dim3(256), 0, stream, qkvb, act);
  hipLaunchKernelGGL(scan_kernel, dim3(64), dim3(128), 0, stream, act, hsb);
  hipLaunchKernelGGL((gemm128<0, 1>), dim3(512 / 128, 4096 / 128), dim3(256), 0, stream,
                     hsb, Wout_b, d_out, x, 4096, 512, 512);
}

// Round 14
// 398.475 us; speedup vs baseline: 1.1014x; 1.1014x over previous
//
#include <hip/hip_runtime.h>

#define S_LEN 512
#define BSZ 8
#define NH 8
#define HD 64
#define IN_DIM 512
#define PROJ 2576   // NH*(5*HD+2)
#define SEG 322     // per-head: 5*64+2
#define AST 352     // act row stride f32: q64,k64,rk64,v64,rv64,beta,rbeta,pad -> 8 rows = 11*1024B
#define CHUNK 8
#define NCH 64      // 512/CHUNK
#define CB (CHUNK * AST * 4)  // 11264 bytes per chunk

typedef __attribute__((ext_vector_type(8))) __bf16 bf16x8;
typedef __attribute__((ext_vector_type(4))) float f32x4;

static __device__ __forceinline__ unsigned short f2bf(float f) {
  unsigned u = __float_as_uint(f);
  unsigned r = (u + 0x7fffu + ((u >> 16) & 1u)) >> 16;
  return (unsigned short)r;
}
static __device__ __forceinline__ float bf2f(unsigned short s) {
  return __uint_as_float(((unsigned)s) << 16);
}

static __device__ __forceinline__ void gl_lds16(const void* g, void* l) {
  __builtin_amdgcn_global_load_lds(
      (const __attribute__((address_space(1))) unsigned int*)g,
      (__attribute__((address_space(3))) unsigned int*)l, 16, 0, 0);
}

// ---------------- prep: LayerNorm (x -> normed bf16) + both weight casts, fused ----------------
// 1024 blocks x 256 threads. Each block: 4 LN rows (one per wave), then grid-stride
// casts of W_slow and W_out to bf16. Replaces 3 launches with 1 (saves ~2 launch gaps).
__global__ __launch_bounds__(256) void prep_kernel(const float* __restrict__ x,
                                                   const float* __restrict__ gamma,
                                                   const float* __restrict__ beta,
                                                   unsigned short* __restrict__ out,
                                                   const float* __restrict__ W_slow,
                                                   unsigned short* __restrict__ Wslow_b,
                                                   const float* __restrict__ W_out,
                                                   unsigned short* __restrict__ Wout_b) {
  int wave = threadIdx.x >> 6, lane = threadIdx.x & 63;
  int row = blockIdx.x * 4 + wave;
  const float* xr = x + (size_t)row * IN_DIM + lane * 8;
  float4 a = *(const float4*)xr;
  float4 b = *(const float4*)(xr + 4);
  float vals[8] = {a.x, a.y, a.z, a.w, b.x, b.y, b.z, b.w};
  float s = 0.f, ss = 0.f;
#pragma unroll
  for (int i = 0; i < 8; i++) { s += vals[i]; ss += vals[i] * vals[i]; }
#pragma unroll
  for (int o = 32; o; o >>= 1) { s += __shfl_xor(s, o); ss += __shfl_xor(ss, o); }
  float mu = s * (1.f / 512.f);
  float var = ss * (1.f / 512.f) - mu * mu;
  float rstd = rsqrtf(var + 1e-5f);
  const float* g = gamma + lane * 8;
  const float* be = beta + lane * 8;
  float4 g1 = *(const float4*)g, g2 = *(const float4*)(g + 4);
  float4 b1 = *(const float4*)be, b2 = *(const float4*)(be + 4);
  float gs[8] = {g1.x, g1.y, g1.z, g1.w, g2.x, g2.y, g2.z, g2.w};
  float bs[8] = {b1.x, b1.y, b1.z, b1.w, b2.x, b2.y, b2.z, b2.w};
  union { unsigned short u[8]; uint4 v; } pk;
#pragma unroll
  for (int i = 0; i < 8; i++) pk.u[i] = f2bf((vals[i] - mu) * rstd * gs[i] + bs[i]);
  *(uint4*)(out + (size_t)row * IN_DIM + lane * 8) = pk.v;

  // grid-stride weight casts (independent of LN; no sync needed)
  int gt = blockIdx.x * 256 + threadIdx.x;
  int gs2 = 1024 * 256;
  for (int i = gt; i < PROJ * 512; i += gs2) Wslow_b[i] = f2bf(W_slow[i]);
  for (int i = gt; i < 512 * 512; i += gs2) Wout_b[i] = f2bf(W_out[i]);
}

// ---------------- GEMM 128x128 tile: C[m][n] = sum_k A[m][k]*B[n][k] ----------------
template <int BF16_OUT, int RESID>
__global__ __launch_bounds__(256) void gemm128(const unsigned short* __restrict__ A,
                                               const unsigned short* __restrict__ B,
                                               void* __restrict__ Cout,
                                               const float* __restrict__ resid,
                                               int M, int N, int K) {
  __shared__ __align__(16) unsigned short As[128 * 32];
  __shared__ __align__(16) unsigned short Bs[128 * 32];
  int tid = threadIdx.x;
  int lane = tid & 63, w = tid >> 6;
  int wr = w >> 1, wc = w & 1;
  int m0 = blockIdx.y * 128, n0 = blockIdx.x * 128;

  int r0 = (w * 2) * 16 + (lane >> 2);
  int r1 = (w * 2 + 1) * 16 + (lane >> 2);
  int kq = (lane & 3) * 8;
  const unsigned short* A0 = A + (size_t)(m0 + r0) * K + kq;
  const unsigned short* A1 = A + (size_t)(m0 + r1) * K + kq;
  int bn0 = n0 + r0; if (bn0 > N - 1) bn0 = N - 1;
  int bn1 = n0 + r1; if (bn1 > N - 1) bn1 = N - 1;
  const unsigned short* B0 = B + (size_t)bn0 * K + kq;
  const unsigned short* B1 = B + (size_t)bn1 * K + kq;
  char* asb0 = (char*)As + (w * 2) * 1024;
  char* asb1 = (char*)As + (w * 2 + 1) * 1024;
  char* bsb0 = (char*)Bs + (w * 2) * 1024;
  char* bsb1 = (char*)Bs + (w * 2 + 1) * 1024;

  f32x4 acc[4][4];
#pragma unroll
  for (int i = 0; i < 4; i++)
#pragma unroll
    for (int j = 0; j < 4; j++) acc[i][j] = (f32x4){0.f, 0.f, 0.f, 0.f};

  int q = lane >> 4, m16 = lane & 15;
  for (int k0 = 0; k0 < K; k0 += 32) {
    gl_lds16(A0 + k0, asb0);
    gl_lds16(A1 + k0, asb1);
    gl_lds16(B0 + k0, bsb0);
    gl_lds16(B1 + k0, bsb1);
    asm volatile("s_waitcnt vmcnt(0)" ::: "memory");
    __syncthreads();
    bf16x8 af[4], bfv[4];
#pragma unroll
    for (int f = 0; f < 4; f++)
      af[f] = *(const bf16x8*)&As[(wr * 64 + f * 16 + m16) * 32 + q * 8];
#pragma unroll
    for (int f = 0; f < 4; f++)
      bfv[f] = *(const bf16x8*)&Bs[(wc * 64 + f * 16 + m16) * 32 + q * 8];
#pragma unroll
    for (int fa = 0; fa < 4; fa++)
#pragma unroll
      for (int fb = 0; fb < 4; fb++)
        acc[fa][fb] = __builtin_amdgcn_mfma_f32_16x16x32_bf16(af[fa], bfv[fb], acc[fa][fb], 0, 0, 0);
    __syncthreads();
  }

#pragma unroll
  for (int fa = 0; fa < 4; fa++) {
#pragma unroll
    for (int fb = 0; fb < 4; fb++) {
#pragma unroll
      for (int rr = 0; rr < 4; rr++) {
        int gm = m0 + wr * 64 + fa * 16 + q * 4 + rr;
        int gn = n0 + wc * 64 + fb * 16 + m16;
        if (gn < N) {
          float v = acc[fa][fb][rr];
          if (BF16_OUT) {
            ((unsigned short*)Cout)[(size_t)gm * N + gn] = f2bf(v);
          } else {
            float o = v;
            if (RESID) o += resid[(size_t)gm * N + gn];
            ((float*)Cout)[(size_t)gm * N + gn] = o;
          }
        }
      }
    }
  }
}

// ---------------- parallel activations -> act stream (f32) ----------------
__global__ __launch_bounds__(256) void act_kernel(const unsigned short* __restrict__ qkvb,
                                                  float* __restrict__ act) {
  int gw = blockIdx.x * 4 + (threadIdx.x >> 6);
  int l = threadIdx.x & 63;
  int m = gw >> 3, hh = gw & 7;
  int t = m >> 3, b = m & 7;
  const unsigned short* src = qkvb + (size_t)m * PROJ + hh * SEG;
  float fq = bf2f(src[l]);
  float fk = bf2f(src[64 + l]);
  float fv = bf2f(src[128 + l]);
  float fr = bf2f(src[192 + l]);
  float frv = bf2f(src[256 + l]);
  float mq = fq, mk = fk, mr = fr;
#pragma unroll
  for (int o = 32; o; o >>= 1) {
    mq = fmaxf(mq, __shfl_xor(mq, o));
    mk = fmaxf(mk, __shfl_xor(mk, o));
    mr = fmaxf(mr, __shfl_xor(mr, o));
  }
  float eq = __expf(fq - mq), ek = __expf(fk - mk), er = __expf(fr - mr);
  float sq = eq, sk = ek, sr = er;
#pragma unroll
  for (int o = 32; o; o >>= 1) {
    sq += __shfl_xor(sq, o);
    sk += __shfl_xor(sk, o);
    sr += __shfl_xor(sr, o);
  }
  int bh = b * 8 + hh;
  float* dst = act + ((size_t)bh * S_LEN + t) * AST;
  dst[l] = eq * __builtin_amdgcn_rcpf(sq);
  dst[64 + l] = ek * __builtin_amdgcn_rcpf(sk);
  dst[128 + l] = er * __builtin_amdgcn_rcpf(sr);
  dst[192 + l] = fv;
  dst[256 + l] = frv;
  if (l < 2) {
    float xv = bf2f(src[320 + l]);
    dst[320 + l] = __builtin_amdgcn_rcpf(1.f + __expf(-xv));
  }
}

// ---------------- scan: async producer/consumer waves (verified round-4 kernel) ----------------
// Block = 128 threads = 2 waves per (b,h). Wave0 (producer): stages act chunks via
// global_load_lds, runs the delta-rule W-scan, deposits z into a 4-chunk LDS ring,
// publishes per-chunk flags. Wave1 (consumer): polls the flag once per chunk (8 steps),
// runs the recurrent R-scan. Byte-identical restore of the 276 us round-4 kernel.
__global__ __launch_bounds__(128, 1) void scan_kernel(const float* __restrict__ act,
                                                      unsigned short* __restrict__ hs) {
  int bh = blockIdx.x;
  int b = bh >> 3, hh = bh & 7;
  int tid = threadIdx.x, l = tid & 63, w = tid >> 6;

  __shared__ __align__(16) float stage[4][CHUNK * AST];
  __shared__ __align__(16) float zring[4][CHUNK][64];
  __shared__ __align__(16) float ehb[64];
  __shared__ int flags[16];  // [0]=w0done (chunks), [8]=w1done (chunks)

  volatile int* w0done = &flags[0];
  volatile int* w1done = &flags[8];

  const char* abase = (const char*)(act + (size_t)bh * S_LEN * AST);

  if (tid == 0) { flags[0] = 0; flags[8] = 0; }
  if (w) ehb[l] = 1.f;  // softmax(h0=0) numerators -> uniform
  if (w == 0) {
    // stage chunk 0
#pragma unroll
    for (int i = 0; i < 11; i++)
      gl_lds16(abase + (size_t)i * 1024 + l * 16, (char*)&stage[0][0] + i * 1024);
  }
  __syncthreads();  // flags/ehb init visible; drains wave0's chunk-0 staging too

  f32x4 M[16];
#pragma unroll
  for (int j = 0; j < 16; j++) M[j] = (f32x4){0.f, 0.f, 0.f, 0.f};
  const f32x4 z4 = {0.f, 0.f, 0.f, 0.f};

  if (w == 0) {
    // ================= producer: W-scan =================
    for (int c = 0; c < NCH; c++) {
      // back-pressure: staging into slot (c+1)&3 overwrites chunk c-3
      if (c >= 3) {
        while (*w1done < c - 2) __builtin_amdgcn_s_sleep(2);
      }
      if (c + 1 < NCH) {
        const char* nb = abase + (size_t)(c + 1) * CB;
        char* sb = (char*)&stage[(c + 1) & 3][0];
#pragma unroll
        for (int i = 0; i < 11; i++)
          gl_lds16(nb + (size_t)i * 1024 + l * 16, sb + i * 1024);
        asm volatile("s_waitcnt vmcnt(11)" ::: "memory");  // chunk c's staging done
      } else {
        asm volatile("s_waitcnt vmcnt(0)" ::: "memory");
      }
      const float* cb = &stage[c & 3][0];
      float* zc = &zring[c & 3][0][0];
#pragma unroll
      for (int s = 0; s < CHUNK; s++) {
        const float* stf = cb + s * AST;
        const f32x4* st4 = (const f32x4*)stf;
        // ---- vold = W.k; fused W += coef*k, z = W.q ----
        float cv = stf[192 + l];
        f32x4 kk[16];
#pragma unroll
        for (int j = 0; j < 16; j++) kk[j] = st4[16 + j];  // k
        f32x4 a0 = z4, a1 = z4, a2 = z4, a3 = z4;
#pragma unroll
        for (int j = 0; j < 16; j += 4) {
          a0 += M[j] * kk[j];
          a1 += M[j + 1] * kk[j + 1];
          a2 += M[j + 2] * kk[j + 2];
          a3 += M[j + 3] * kk[j + 3];
        }
        f32x4 vo = (a0 + a1) + (a2 + a3);
        float vold = (vo.x + vo.y) + (vo.z + vo.w);
        float bt = stf[320];
        float coef = bt * (cv - vold);
        f32x4 c4 = {coef, coef, coef, coef};
        a0 = a1 = a2 = a3 = z4;
#pragma unroll
        for (int j = 0; j < 16; j += 4) {
          M[j] += c4 * kk[j];         a0 += M[j] * st4[j];
          M[j + 1] += c4 * kk[j + 1]; a1 += M[j + 1] * st4[j + 1];
          M[j + 2] += c4 * kk[j + 2]; a2 += M[j + 2] * st4[j + 2];
          M[j + 3] += c4 * kk[j + 3]; a3 += M[j + 3] * st4[j + 3];
        }
        vo = (a0 + a1) + (a2 + a3);
        zc[s * 64 + l] = (vo.x + vo.y) + (vo.z + vo.w);
      }
      asm volatile("s_waitcnt lgkmcnt(0)" ::: "memory");  // z writes retired
      *w0done = c + 1;
    }
  } else {
    // ================= consumer: R-scan =================
    unsigned short* hdst = hs + (size_t)b * 512 + hh * 64 + l;
    for (int c = 0; c < NCH; c++) {
      while (*w0done < c + 1) __builtin_amdgcn_s_sleep(2);  // chunk c staged + z ready
      const float* cb = &stage[c & 3][0];
      const float* zc = &zring[c & 3][0][0];
#pragma unroll
      for (int s = 0; s < CHUNK; s++) {
        const float* stf = cb + s * AST;
        const f32x4* st4 = (const f32x4*)stf;
        float z = zc[s * 64 + l];  // issue early; latency hides under matvec
        // ---- rvold = R.rk; fused R += rcoef*rk, hp = R.eh, sm = sum(eh) ----
        float cv = stf[256 + l];
        f32x4 kk[16];
#pragma unroll
        for (int j = 0; j < 16; j++) kk[j] = st4[32 + j];  // rk
        f32x4 a0 = z4, a1 = z4, a2 = z4, a3 = z4;
#pragma unroll
        for (int j = 0; j < 16; j += 4) {
          a0 += M[j] * kk[j];
          a1 += M[j + 1] * kk[j + 1];
          a2 += M[j + 2] * kk[j + 2];
          a3 += M[j + 3] * kk[j + 3];
        }
        f32x4 vo = (a0 + a1) + (a2 + a3);
        float rvold = (vo.x + vo.y) + (vo.z + vo.w);
        float rb = stf[321];
        float rcoef = rb * (cv - rvold);
        f32x4 c4 = {rcoef, rcoef, rcoef, rcoef};
        const f32x4* e4 = (const f32x4*)ehb;
        f32x4 s0 = z4, s1 = z4, s2v = z4, s3 = z4;
        a0 = a1 = a2 = a3 = z4;
#pragma unroll
        for (int j = 0; j < 16; j += 4) {
          f32x4 e0 = e4[j], e1 = e4[j + 1], e2 = e4[j + 2], e3 = e4[j + 3];
          M[j] += c4 * kk[j];         a0 += M[j] * e0;       s0 += e0;
          M[j + 1] += c4 * kk[j + 1]; a1 += M[j + 1] * e1;   s1 += e1;
          M[j + 2] += c4 * kk[j + 2]; a2 += M[j + 2] * e2;   s2v += e2;
          M[j + 3] += c4 * kk[j + 3]; a3 += M[j + 3] * e3;   s3 += e3;
        }
        f32x4 ho = (a0 + a1) + (a2 + a3);
        f32x4 so = (s0 + s1) + (s2v + s3);
        float hp = (ho.x + ho.y) + (ho.z + ho.w);
        float sm = (so.x + so.y) + (so.z + so.w);
        float h = z + hp * __builtin_amdgcn_rcpf(sm);
        hdst[(size_t)(c * CHUNK + s) * (BSZ * 512)] = f2bf(h);
        // shift-invariant: exp(h-20) keeps qh = eh/sum exact, guards overflow.
        // same-wave DS ordering makes it visible to next step's e4 reads.
        ehb[l] = __expf(h - 20.f);
      }
      asm volatile("s_waitcnt lgkmcnt(0)" ::: "memory");  // all chunk-c reads retired
      *w1done = c + 1;
    }
  }
}

extern "C" void kernel_launch(void* const* d_in, const int* in_sizes, int n_in,
                              void* d_out, int out_size, void* d_ws, size_t ws_size,
                              hipStream_t stream) {
  const float* x = (const float*)d_in[0];
  const float* W_slow = (const float*)d_in[1];
  const float* W_out = (const float*)d_in[2];
  const float* gamma = (const float*)d_in[3];
  const float* beta = (const float*)d_in[4];

  char* ws = (char*)d_ws;
  size_t off = 0;
  unsigned short* normed = (unsigned short*)(ws + off); off += (size_t)4096 * 512 * 2;
  unsigned short* Wslow_b = (unsigned short*)(ws + off); off += (size_t)PROJ * 512 * 2;
  unsigned short* Wout_b = (unsigned short*)(ws + off); off += (size_t)512 * 512 * 2;
  unsigned short* qkvb = (unsigned short*)(ws + off); off += (size_t)4096 * PROJ * 2;
  float* act = (float*)(ws + off); off += (size_t)64 * S_LEN * AST * 4;
  unsigned short* hsb = normed;  // normed is dead after gemm1; reuse for hs

  hipLaunchKernelGGL(prep_kernel, dim3(1024), dim3(256), 0, stream,
                     x, gamma, beta, normed, W_slow, Wslow_b, W_out, Wout_b);
  hipLaunchKernelGGL((gemm128<1, 0>), dim3((PROJ + 127) / 128, 4096 / 128), dim3(256), 0, stream,
                     normed, Wslow_b, (void*)qkvb, (const float*)nullptr, 4096, PROJ, 512);
  hipLaunchKernelGGL(act_kernel, dim3(8192), dim3(256), 0, stream, qkvb, act);
  hipLaunchKernelGGL(scan_kernel, dim3(64), dim3(128), 0, stream, act, hsb);
  hipLaunchKernelGGL((gemm128<0, 1>), dim3(512 / 128, 4096 / 128), dim3(256), 0, stream,
                     hsb, Wout_b, d_out, x, 4096, 512, 512);
}

// Round 15
// 397.769 us; speedup vs baseline: 1.1033x; 1.0018x over previous
//
#include <hip/hip_runtime.h>

#define S_LEN 512
#define BSZ 8
#define NH 8
#define HD 64
#define IN_DIM 512
#define PROJ 2576   // NH*(5*HD+2)
#define SEG 322     // per-head: 5*64+2
#define AST 352     // act row stride f32: q64,k64,rk64,v64,rv64,beta,rbeta,pad -> 8 rows = 11*1024B
#define CHUNK 8
#define NCH 64      // 512/CHUNK
#define CB (CHUNK * AST * 4)  // 11264 bytes per chunk

typedef __attribute__((ext_vector_type(8))) __bf16 bf16x8;
typedef __attribute__((ext_vector_type(4))) float f32x4;

static __device__ __forceinline__ unsigned short f2bf(float f) {
  unsigned u = __float_as_uint(f);
  unsigned r = (u + 0x7fffu + ((u >> 16) & 1u)) >> 16;
  return (unsigned short)r;
}
static __device__ __forceinline__ float bf2f(unsigned short s) {
  return __uint_as_float(((unsigned)s) << 16);
}

static __device__ __forceinline__ void gl_lds16(const void* g, void* l) {
  __builtin_amdgcn_global_load_lds(
      (const __attribute__((address_space(1))) unsigned int*)g,
      (__attribute__((address_space(3))) unsigned int*)l, 16, 0, 0);
}

// ---------------- prep: LayerNorm (x -> normed bf16) + both weight casts, fused ----------------
__global__ __launch_bounds__(256) void prep_kernel(const float* __restrict__ x,
                                                   const float* __restrict__ gamma,
                                                   const float* __restrict__ beta,
                                                   unsigned short* __restrict__ out,
                                                   const float* __restrict__ W_slow,
                                                   unsigned short* __restrict__ Wslow_b,
                                                   const float* __restrict__ W_out,
                                                   unsigned short* __restrict__ Wout_b) {
  int wave = threadIdx.x >> 6, lane = threadIdx.x & 63;
  int row = blockIdx.x * 4 + wave;
  const float* xr = x + (size_t)row * IN_DIM + lane * 8;
  float4 a = *(const float4*)xr;
  float4 b = *(const float4*)(xr + 4);
  float vals[8] = {a.x, a.y, a.z, a.w, b.x, b.y, b.z, b.w};
  float s = 0.f, ss = 0.f;
#pragma unroll
  for (int i = 0; i < 8; i++) { s += vals[i]; ss += vals[i] * vals[i]; }
#pragma unroll
  for (int o = 32; o; o >>= 1) { s += __shfl_xor(s, o); ss += __shfl_xor(ss, o); }
  float mu = s * (1.f / 512.f);
  float var = ss * (1.f / 512.f) - mu * mu;
  float rstd = rsqrtf(var + 1e-5f);
  const float* g = gamma + lane * 8;
  const float* be = beta + lane * 8;
  float4 g1 = *(const float4*)g, g2 = *(const float4*)(g + 4);
  float4 b1 = *(const float4*)be, b2 = *(const float4*)(be + 4);
  float gs[8] = {g1.x, g1.y, g1.z, g1.w, g2.x, g2.y, g2.z, g2.w};
  float bs[8] = {b1.x, b1.y, b1.z, b1.w, b2.x, b2.y, b2.z, b2.w};
  union { unsigned short u[8]; uint4 v; } pk;
#pragma unroll
  for (int i = 0; i < 8; i++) pk.u[i] = f2bf((vals[i] - mu) * rstd * gs[i] + bs[i]);
  *(uint4*)(out + (size_t)row * IN_DIM + lane * 8) = pk.v;

  // grid-stride weight casts (independent of LN; no sync needed)
  int gt = blockIdx.x * 256 + threadIdx.x;
  int gs2 = 1024 * 256;
  for (int i = gt; i < PROJ * 512; i += gs2) Wslow_b[i] = f2bf(W_slow[i]);
  for (int i = gt; i < 512 * 512; i += gs2) Wout_b[i] = f2bf(W_out[i]);
}

// ---------------- GEMM 128x128 tile: C[m][n] = sum_k A[m][k]*B[n][k] ----------------
template <int BF16_OUT, int RESID>
__global__ __launch_bounds__(256) void gemm128(const unsigned short* __restrict__ A,
                                               const unsigned short* __restrict__ B,
                                               void* __restrict__ Cout,
                                               const float* __restrict__ resid,
                                               int M, int N, int K) {
  __shared__ __align__(16) unsigned short As[128 * 32];
  __shared__ __align__(16) unsigned short Bs[128 * 32];
  int tid = threadIdx.x;
  int lane = tid & 63, w = tid >> 6;
  int wr = w >> 1, wc = w & 1;
  int m0 = blockIdx.y * 128, n0 = blockIdx.x * 128;

  int r0 = (w * 2) * 16 + (lane >> 2);
  int r1 = (w * 2 + 1) * 16 + (lane >> 2);
  int kq = (lane & 3) * 8;
  const unsigned short* A0 = A + (size_t)(m0 + r0) * K + kq;
  const unsigned short* A1 = A + (size_t)(m0 + r1) * K + kq;
  int bn0 = n0 + r0; if (bn0 > N - 1) bn0 = N - 1;
  int bn1 = n0 + r1; if (bn1 > N - 1) bn1 = N - 1;
  const unsigned short* B0 = B + (size_t)bn0 * K + kq;
  const unsigned short* B1 = B + (size_t)bn1 * K + kq;
  char* asb0 = (char*)As + (w * 2) * 1024;
  char* asb1 = (char*)As + (w * 2 + 1) * 1024;
  char* bsb0 = (char*)Bs + (w * 2) * 1024;
  char* bsb1 = (char*)Bs + (w * 2 + 1) * 1024;

  f32x4 acc[4][4];
#pragma unroll
  for (int i = 0; i < 4; i++)
#pragma unroll
    for (int j = 0; j < 4; j++) acc[i][j] = (f32x4){0.f, 0.f, 0.f, 0.f};

  int q = lane >> 4, m16 = lane & 15;
  for (int k0 = 0; k0 < K; k0 += 32) {
    gl_lds16(A0 + k0, asb0);
    gl_lds16(A1 + k0, asb1);
    gl_lds16(B0 + k0, bsb0);
    gl_lds16(B1 + k0, bsb1);
    asm volatile("s_waitcnt vmcnt(0)" ::: "memory");
    __syncthreads();
    bf16x8 af[4], bfv[4];
#pragma unroll
    for (int f = 0; f < 4; f++)
      af[f] = *(const bf16x8*)&As[(wr * 64 + f * 16 + m16) * 32 + q * 8];
#pragma unroll
    for (int f = 0; f < 4; f++)
      bfv[f] = *(const bf16x8*)&Bs[(wc * 64 + f * 16 + m16) * 32 + q * 8];
#pragma unroll
    for (int fa = 0; fa < 4; fa++)
#pragma unroll
      for (int fb = 0; fb < 4; fb++)
        acc[fa][fb] = __builtin_amdgcn_mfma_f32_16x16x32_bf16(af[fa], bfv[fb], acc[fa][fb], 0, 0, 0);
    __syncthreads();
  }

#pragma unroll
  for (int fa = 0; fa < 4; fa++) {
#pragma unroll
    for (int fb = 0; fb < 4; fb++) {
#pragma unroll
      for (int rr = 0; rr < 4; rr++) {
        int gm = m0 + wr * 64 + fa * 16 + q * 4 + rr;
        int gn = n0 + wc * 64 + fb * 16 + m16;
        if (gn < N) {
          float v = acc[fa][fb][rr];
          if (BF16_OUT) {
            ((unsigned short*)Cout)[(size_t)gm * N + gn] = f2bf(v);
          } else {
            float o = v;
            if (RESID) o += resid[(size_t)gm * N + gn];
            ((float*)Cout)[(size_t)gm * N + gn] = o;
          }
        }
      }
    }
  }
}

// ---------------- parallel activations -> act stream (f32) ----------------
__global__ __launch_bounds__(256) void act_kernel(const unsigned short* __restrict__ qkvb,
                                                  float* __restrict__ act) {
  int gw = blockIdx.x * 4 + (threadIdx.x >> 6);
  int l = threadIdx.x & 63;
  int m = gw >> 3, hh = gw & 7;
  int t = m >> 3, b = m & 7;
  const unsigned short* src = qkvb + (size_t)m * PROJ + hh * SEG;
  float fq = bf2f(src[l]);
  float fk = bf2f(src[64 + l]);
  float fv = bf2f(src[128 + l]);
  float fr = bf2f(src[192 + l]);
  float frv = bf2f(src[256 + l]);
  float mq = fq, mk = fk, mr = fr;
#pragma unroll
  for (int o = 32; o; o >>= 1) {
    mq = fmaxf(mq, __shfl_xor(mq, o));
    mk = fmaxf(mk, __shfl_xor(mk, o));
    mr = fmaxf(mr, __shfl_xor(mr, o));
  }
  float eq = __expf(fq - mq), ek = __expf(fk - mk), er = __expf(fr - mr);
  float sq = eq, sk = ek, sr = er;
#pragma unroll
  for (int o = 32; o; o >>= 1) {
    sq += __shfl_xor(sq, o);
    sk += __shfl_xor(sk, o);
    sr += __shfl_xor(sr, o);
  }
  int bh = b * 8 + hh;
  float* dst = act + ((size_t)bh * S_LEN + t) * AST;
  dst[l] = eq * __builtin_amdgcn_rcpf(sq);
  dst[64 + l] = ek * __builtin_amdgcn_rcpf(sk);
  dst[128 + l] = er * __builtin_amdgcn_rcpf(sr);
  dst[192 + l] = fv;
  dst[256 + l] = frv;
  if (l < 2) {
    float xv = bf2f(src[320 + l]);
    dst[320 + l] = __builtin_amdgcn_rcpf(1.f + __expf(-xv));
  }
}

// ---------------- scan: R4 async skeleton + 1-wave/EU register budget ----------------
// Block = 128 threads = 2 waves per (b,h), one per SIMD. Wave0 (producer): stages act
// chunks via global_load_lds, runs the delta-rule W-scan, deposits z into a 4-chunk LDS
// ring, publishes per-chunk flags. Wave1 (consumer): polls the flag once per chunk,
// runs the recurrent R-scan. Source byte-identical to the verified 276us round-4 kernel;
// ONLY change: amdgpu_waves_per_eu(1,1) pins the allocator's occupancy target to our
// actual occupancy (1 wave/EU), raising the VGPR budget to 512 so kk[16] (64 regs) can
// stay resident across pass-1 -> pass-2 (eliminates the 16 re-read ds_read_b128/step
// forced by the default 96-reg allocation).
__global__ __launch_bounds__(128, 1) __attribute__((amdgpu_waves_per_eu(1, 1)))
void scan_kernel(const float* __restrict__ act,
                 unsigned short* __restrict__ hs) {
  int bh = blockIdx.x;
  int b = bh >> 3, hh = bh & 7;
  int tid = threadIdx.x, l = tid & 63, w = tid >> 6;

  __shared__ __align__(16) float stage[4][CHUNK * AST];
  __shared__ __align__(16) float zring[4][CHUNK][64];
  __shared__ __align__(16) float ehb[64];
  __shared__ int flags[16];  // [0]=w0done (chunks), [8]=w1done (chunks)

  volatile int* w0done = &flags[0];
  volatile int* w1done = &flags[8];

  const char* abase = (const char*)(act + (size_t)bh * S_LEN * AST);

  if (tid == 0) { flags[0] = 0; flags[8] = 0; }
  if (w) ehb[l] = 1.f;  // softmax(h0=0) numerators -> uniform
  if (w == 0) {
    // stage chunk 0
#pragma unroll
    for (int i = 0; i < 11; i++)
      gl_lds16(abase + (size_t)i * 1024 + l * 16, (char*)&stage[0][0] + i * 1024);
  }
  __syncthreads();  // flags/ehb init visible; drains wave0's chunk-0 staging too

  f32x4 M[16];
#pragma unroll
  for (int j = 0; j < 16; j++) M[j] = (f32x4){0.f, 0.f, 0.f, 0.f};
  const f32x4 z4 = {0.f, 0.f, 0.f, 0.f};

  if (w == 0) {
    // ================= producer: W-scan =================
    for (int c = 0; c < NCH; c++) {
      // back-pressure: staging into slot (c+1)&3 overwrites chunk c-3
      if (c >= 3) {
        while (*w1done < c - 2) __builtin_amdgcn_s_sleep(2);
      }
      if (c + 1 < NCH) {
        const char* nb = abase + (size_t)(c + 1) * CB;
        char* sb = (char*)&stage[(c + 1) & 3][0];
#pragma unroll
        for (int i = 0; i < 11; i++)
          gl_lds16(nb + (size_t)i * 1024 + l * 16, sb + i * 1024);
        asm volatile("s_waitcnt vmcnt(11)" ::: "memory");  // chunk c's staging done
      } else {
        asm volatile("s_waitcnt vmcnt(0)" ::: "memory");
      }
      const float* cb = &stage[c & 3][0];
      float* zc = &zring[c & 3][0][0];
#pragma unroll
      for (int s = 0; s < CHUNK; s++) {
        const float* stf = cb + s * AST;
        const f32x4* st4 = (const f32x4*)stf;
        // ---- vold = W.k; fused W += coef*k, z = W.q ----
        float cv = stf[192 + l];
        f32x4 kk[16];
#pragma unroll
        for (int j = 0; j < 16; j++) kk[j] = st4[16 + j];  // k
        f32x4 a0 = z4, a1 = z4, a2 = z4, a3 = z4;
#pragma unroll
        for (int j = 0; j < 16; j += 4) {
          a0 += M[j] * kk[j];
          a1 += M[j + 1] * kk[j + 1];
          a2 += M[j + 2] * kk[j + 2];
          a3 += M[j + 3] * kk[j + 3];
        }
        f32x4 vo = (a0 + a1) + (a2 + a3);
        float vold = (vo.x + vo.y) + (vo.z + vo.w);
        float bt = stf[320];
        float coef = bt * (cv - vold);
        f32x4 c4 = {coef, coef, coef, coef};
        a0 = a1 = a2 = a3 = z4;
#pragma unroll
        for (int j = 0; j < 16; j += 4) {
          M[j] += c4 * kk[j];         a0 += M[j] * st4[j];
          M[j + 1] += c4 * kk[j + 1]; a1 += M[j + 1] * st4[j + 1];
          M[j + 2] += c4 * kk[j + 2]; a2 += M[j + 2] * st4[j + 2];
          M[j + 3] += c4 * kk[j + 3]; a3 += M[j + 3] * st4[j + 3];
        }
        vo = (a0 + a1) + (a2 + a3);
        zc[s * 64 + l] = (vo.x + vo.y) + (vo.z + vo.w);
      }
      asm volatile("s_waitcnt lgkmcnt(0)" ::: "memory");  // z writes retired
      *w0done = c + 1;
    }
  } else {
    // ================= consumer: R-scan =================
    unsigned short* hdst = hs + (size_t)b * 512 + hh * 64 + l;
    for (int c = 0; c < NCH; c++) {
      while (*w0done < c + 1) __builtin_amdgcn_s_sleep(2);  // chunk c staged + z ready
      const float* cb = &stage[c & 3][0];
      const float* zc = &zring[c & 3][0][0];
#pragma unroll
      for (int s = 0; s < CHUNK; s++) {
        const float* stf = cb + s * AST;
        const f32x4* st4 = (const f32x4*)stf;
        float z = zc[s * 64 + l];  // issue early; latency hides under matvec
        // ---- rvold = R.rk; fused R += rcoef*rk, hp = R.eh, sm = sum(eh) ----
        float cv = stf[256 + l];
        f32x4 kk[16];
#pragma unroll
        for (int j = 0; j < 16; j++) kk[j] = st4[32 + j];  // rk
        f32x4 a0 = z4, a1 = z4, a2 = z4, a3 = z4;
#pragma unroll
        for (int j = 0; j < 16; j += 4) {
          a0 += M[j] * kk[j];
          a1 += M[j + 1] * kk[j + 1];
          a2 += M[j + 2] * kk[j + 2];
          a3 += M[j + 3] * kk[j + 3];
        }
        f32x4 vo = (a0 + a1) + (a2 + a3);
        float rvold = (vo.x + vo.y) + (vo.z + vo.w);
        float rb = stf[321];
        float rcoef = rb * (cv - rvold);
        f32x4 c4 = {rcoef, rcoef, rcoef, rcoef};
        const f32x4* e4 = (const f32x4*)ehb;
        f32x4 s0 = z4, s1 = z4, s2v = z4, s3 = z4;
        a0 = a1 = a2 = a3 = z4;
#pragma unroll
        for (int j = 0; j < 16; j += 4) {
          f32x4 e0 = e4[j], e1 = e4[j + 1], e2 = e4[j + 2], e3 = e4[j + 3];
          M[j] += c4 * kk[j];         a0 += M[j] * e0;       s0 += e0;
          M[j + 1] += c4 * kk[j + 1]; a1 += M[j + 1] * e1;   s1 += e1;
          M[j + 2] += c4 * kk[j + 2]; a2 += M[j + 2] * e2;   s2v += e2;
          M[j + 3] += c4 * kk[j + 3]; a3 += M[j + 3] * e3;   s3 += e3;
        }
        f32x4 ho = (a0 + a1) + (a2 + a3);
        f32x4 so = (s0 + s1) + (s2v + s3);
        float hp = (ho.x + ho.y) + (ho.z + ho.w);
        float sm = (so.x + so.y) + (so.z + so.w);
        float h = z + hp * __builtin_amdgcn_rcpf(sm);
        hdst[(size_t)(c * CHUNK + s) * (BSZ * 512)] = f2bf(h);
        // shift-invariant: exp(h-20) keeps qh = eh/sum exact, guards overflow.
        // same-wave DS ordering makes it visible to next step's e4 reads.
        ehb[l] = __expf(h - 20.f);
      }
      asm volatile("s_waitcnt lgkmcnt(0)" ::: "memory");  // all chunk-c reads retired
      *w1done = c + 1;
    }
  }
}

extern "C" void kernel_launch(void* const* d_in, const int* in_sizes, int n_in,
                              void* d_out, int out_size, void* d_ws, size_t ws_size,
                              hipStream_t stream) {
  const float* x = (const float*)d_in[0];
  const float* W_slow = (const float*)d_in[1];
  const float* W_out = (const float*)d_in[2];
  const float* gamma = (const float*)d_in[3];
  const float* beta = (const float*)d_in[4];

  char* ws = (char*)d_ws;
  size_t off = 0;
  unsigned short* normed = (unsigned short*)(ws + off); off += (size_t)4096 * 512 * 2;
  unsigned short* Wslow_b = (unsigned short*)(ws + off); off += (size_t)PROJ * 512 * 2;
  unsigned short* Wout_b = (unsigned short*)(ws + off); off += (size_t)512 * 512 * 2;
  unsigned short* qkvb = (unsigned short*)(ws + off); off += (size_t)4096 * PROJ * 2;
  float* act = (float*)(ws + off); off += (size_t)64 * S_LEN * AST * 4;
  unsigned short* hsb = normed;  // normed is dead after gemm1; reuse for hs

  hipLaunchKernelGGL(prep_kernel, dim3(1024), dim3(256), 0, stream,
                     x, gamma, beta, normed, W_slow, Wslow_b, W_out, Wout_b);
  hipLaunchKernelGGL((gemm128<1, 0>), dim3((PROJ + 127) / 128, 4096 / 128), dim3(256), 0, stream,
                     normed, Wslow_b, (void*)qkvb, (const float*)nullptr, 4096, PROJ, 512);
  hipLaunchKernelGGL(act_kernel, dim3(8192), dim3(256), 0, stream, qkvb, act);
  hipLaunchKernelGGL(scan_kernel, dim3(64), dim3(128), 0, stream, act, hsb);
  hipLaunchKernelGGL((gemm128<0, 1>), dim3(512 / 128, 4096 / 128), dim3(256), 0, stream,
                     hsb, Wout_b, d_out, x, 4096, 512, 512);
}